// Round 1
// baseline (2272.804 us; speedup 1.0000x reference)
//
#include <hip/hip_runtime.h>

// GraphSAGE 3-layer + BN(train stats) + ReLU + classifier, MI355X.
// Pipeline per call:
//   1. CSR build (histogram + 1-block scan + scatter fill)  -- no per-feature atomics
//   2. per layer: mean-aggregate (wave/node, bf16 gather, f32 acc) -> M
//      GEMM h = M@w_l^T + h_prev@w_r^T + b (f32 compute, bf16 A, f32 W)
//      BN stats (column sum/sumsq) -> finalize scale/shift -> apply+ReLU (bf16 in-place)
//   3. classifier GEMM -> f32 d_out
// Activations stored bf16 (threshold is 2% of max; bf16 quant ~0.2%).

#define DEV static __device__ __forceinline__

DEV float bf2f(unsigned short u) { return __uint_as_float(((unsigned)u) << 16); }
DEV unsigned short f2bf(float f) {
    unsigned u = __float_as_uint(f);
    unsigned r = u + 0x7fffu + ((u >> 16) & 1u);  // round-nearest-even
    return (unsigned short)(r >> 16);
}

// ---------------- CSR build ----------------

__global__ void detect_i64(const int* ei, int* flag) {
    // int64 little-endian with values < 2^31 => odd 32-bit words are 0
    int z = (ei[1] == 0) & (ei[3] == 0) & (ei[5] == 0) & (ei[7] == 0);
    *flag = z;
}

__global__ void hist_kernel(const int* __restrict__ ei, const int* __restrict__ flag,
                            int E, int* __restrict__ cnt) {
    const bool i64 = (*flag != 0);
    for (int e = blockIdx.x * blockDim.x + threadIdx.x; e < E; e += gridDim.x * blockDim.x) {
        int d = i64 ? ei[2 * (E + e)] : ei[E + e];
        atomicAdd(&cnt[d], 1);
    }
}

__global__ void scan_kernel(const int* __restrict__ cnt, int* __restrict__ rp,
                            int* __restrict__ pos, int n) {
    __shared__ int sums[1024];
    int t = threadIdx.x;
    int chunk = (n + 1023) >> 10;
    int start = t * chunk;
    int end = min(start + chunk, n);
    int s = 0;
    for (int i = start; i < end; ++i) s += cnt[i];
    sums[t] = s;
    __syncthreads();
    for (int off = 1; off < 1024; off <<= 1) {
        int v = 0;
        if (t >= off) v = sums[t - off];
        __syncthreads();
        sums[t] += v;
        __syncthreads();
    }
    int run = sums[t] - s;  // exclusive prefix of this thread's chunk
    for (int i = start; i < end; ++i) {
        rp[i] = run;
        pos[i] = run;
        run += cnt[i];
    }
    if (t == 1023) rp[n] = sums[1023];
}

__global__ void fill_kernel(const int* __restrict__ ei, const int* __restrict__ flag,
                            int E, int* __restrict__ pos, int* __restrict__ csr) {
    const bool i64 = (*flag != 0);
    for (int e = blockIdx.x * blockDim.x + threadIdx.x; e < E; e += gridDim.x * blockDim.x) {
        int s = i64 ? ei[2 * e] : ei[e];
        int d = i64 ? ei[2 * (E + e)] : ei[E + e];
        int p = atomicAdd(&pos[d], 1);
        csr[p] = s;
    }
}

// ---------------- dtype convert ----------------

__global__ void f32_to_bf16_kernel(const float* __restrict__ x, unsigned short* __restrict__ o, int n4) {
    for (int i = blockIdx.x * blockDim.x + threadIdx.x; i < n4; i += gridDim.x * blockDim.x) {
        float4 v = ((const float4*)x)[i];
        ushort4 r;
        r.x = f2bf(v.x); r.y = f2bf(v.y); r.z = f2bf(v.z); r.w = f2bf(v.w);
        ((ushort4*)o)[i] = r;
    }
}

// ---------------- mean aggregation (wave per node) ----------------

template <int VEC>  // cols = 64*VEC
__global__ void agg_mean(const unsigned short* __restrict__ X, const int* __restrict__ rp,
                         const int* __restrict__ csr, unsigned short* __restrict__ M, int n) {
    const int cols = VEC * 64;
    int w = blockIdx.x * (blockDim.x >> 6) + (threadIdx.x >> 6);
    int lane = threadIdx.x & 63;
    if (w >= n) return;
    int beg = rp[w], end = rp[w + 1];
    float acc[VEC];
#pragma unroll
    for (int i = 0; i < VEC; ++i) acc[i] = 0.f;
    for (int e = beg; e < end; ++e) {
        int j = csr[e];
        const unsigned short* p = X + (size_t)j * cols + lane * VEC;
        if (VEC == 2) {
            unsigned u = *(const unsigned*)p;
            acc[0] += __uint_as_float(u << 16);
            acc[1] += __uint_as_float(u & 0xffff0000u);
        } else {
            uint2 u = *(const uint2*)p;
            acc[0] += __uint_as_float(u.x << 16);
            acc[1] += __uint_as_float(u.x & 0xffff0000u);
            acc[2] += __uint_as_float(u.y << 16);
            acc[3] += __uint_as_float(u.y & 0xffff0000u);
        }
    }
    float inv = 1.0f / (float)max(end - beg, 1);
    unsigned short* q = M + (size_t)w * cols + lane * VEC;
    if (VEC == 2) {
        *(ushort2*)q = make_ushort2(f2bf(acc[0] * inv), f2bf(acc[1] * inv));
    } else {
        *(ushort4*)q = make_ushort4(f2bf(acc[0] * inv), f2bf(acc[1] * inv),
                                    f2bf(acc[2] * inv), f2bf(acc[3] * inv));
    }
}

// ---------------- dual-source GEMM: C = A0@W0^T + A1@W1^T + bias ----------------
// A: [n,K] bf16 row-major; W: [outc,K] f32 row-major; C: bf16 or f32 [n,outc].
// 64x64 tile, 256 threads (16x16), 4x4 microtile, K-chunk 32.

__launch_bounds__(256)
__global__ void gemm_dual(const unsigned short* __restrict__ A0, const float* __restrict__ W0,
                          const unsigned short* __restrict__ A1, const float* __restrict__ W1,
                          const float* __restrict__ bias, int n, int K, int outc,
                          unsigned short* __restrict__ Cbf, float* __restrict__ Cf) {
    __shared__ float As[64][36];  // [row][k] pad->row stride 144B (16B aligned)
    __shared__ float Wt[32][68];  // [k][col] transposed; col-reads 2-way (free)

    const int t = threadIdx.x;
    const int ty = t >> 4, tx = t & 15;
    const int row0 = blockIdx.x * 64;
    const int col0 = blockIdx.y * 64;
    const int lr = t >> 2;          // 0..63
    const int seg = (t & 3) * 8;    // 0,8,16,24 (k offset within chunk)

    float acc[4][4] = {};

    for (int srcsel = 0; srcsel < 2; ++srcsel) {
        const unsigned short* A = srcsel ? A1 : A0;
        const float* W = srcsel ? W1 : W0;
        if (A == nullptr) break;  // uniform across block
        for (int kc = 0; kc < K; kc += 32) {
            // --- stage A tile (bf16 -> f32) ---
            int ar = row0 + lr;
            uint4 av = make_uint4(0u, 0u, 0u, 0u);
            if (ar < n) av = *(const uint4*)(A + (size_t)ar * K + kc + seg);
            float4 lo, hi;
            lo.x = __uint_as_float(av.x << 16); lo.y = __uint_as_float(av.x & 0xffff0000u);
            lo.z = __uint_as_float(av.y << 16); lo.w = __uint_as_float(av.y & 0xffff0000u);
            hi.x = __uint_as_float(av.z << 16); hi.y = __uint_as_float(av.z & 0xffff0000u);
            hi.z = __uint_as_float(av.w << 16); hi.w = __uint_as_float(av.w & 0xffff0000u);
            // --- stage W tile transposed ---
            int wr = col0 + lr;
            float wv[8];
#pragma unroll
            for (int m = 0; m < 8; ++m) wv[m] = 0.f;
            if (wr < outc) {
                const float* wp = W + (size_t)wr * K + kc + seg;
                float4 w0v = *(const float4*)wp;
                float4 w1v = *(const float4*)(wp + 4);
                wv[0] = w0v.x; wv[1] = w0v.y; wv[2] = w0v.z; wv[3] = w0v.w;
                wv[4] = w1v.x; wv[5] = w1v.y; wv[6] = w1v.z; wv[7] = w1v.w;
            }
            *(float4*)&As[lr][seg] = lo;
            *(float4*)&As[lr][seg + 4] = hi;
#pragma unroll
            for (int m = 0; m < 8; ++m) Wt[seg + m][lr] = wv[m];
            __syncthreads();
            // --- compute ---
#pragma unroll
            for (int kk = 0; kk < 32; kk += 4) {
                float4 a0 = *(const float4*)&As[ty * 4 + 0][kk];
                float4 a1 = *(const float4*)&As[ty * 4 + 1][kk];
                float4 a2 = *(const float4*)&As[ty * 4 + 2][kk];
                float4 a3 = *(const float4*)&As[ty * 4 + 3][kk];
                float4 b0 = *(const float4*)&Wt[kk + 0][tx * 4];
                float4 b1 = *(const float4*)&Wt[kk + 1][tx * 4];
                float4 b2 = *(const float4*)&Wt[kk + 2][tx * 4];
                float4 b3 = *(const float4*)&Wt[kk + 3][tx * 4];
#define ROWFMA(i, A4)                                                        \
                acc[i][0] += A4.x * b0.x + A4.y * b1.x + A4.z * b2.x + A4.w * b3.x; \
                acc[i][1] += A4.x * b0.y + A4.y * b1.y + A4.z * b2.y + A4.w * b3.y; \
                acc[i][2] += A4.x * b0.z + A4.y * b1.z + A4.z * b2.z + A4.w * b3.z; \
                acc[i][3] += A4.x * b0.w + A4.y * b1.w + A4.z * b2.w + A4.w * b3.w;
                ROWFMA(0, a0) ROWFMA(1, a1) ROWFMA(2, a2) ROWFMA(3, a3)
#undef ROWFMA
            }
            __syncthreads();
        }
    }
    // --- epilogue ---
#pragma unroll
    for (int i = 0; i < 4; ++i) {
        int r = row0 + ty * 4 + i;
        if (r >= n) continue;
#pragma unroll
        for (int j = 0; j < 4; ++j) {
            int c = col0 + tx * 4 + j;
            if (c >= outc) continue;
            float v = acc[i][j] + bias[c];
            if (Cf) Cf[(size_t)r * outc + c] = v;
            else Cbf[(size_t)r * outc + c] = f2bf(v);
        }
    }
}

// ---------------- BatchNorm (training stats) + ReLU ----------------

__global__ void bn_stats(const unsigned short* __restrict__ H, int n, int c,
                         float* __restrict__ s0, float* __restrict__ s1) {
    int col = threadIdx.x;
    if (col >= c) return;
    float s = 0.f, q = 0.f;
    for (int r = blockIdx.x; r < n; r += gridDim.x) {
        float v = bf2f(H[(size_t)r * c + col]);
        s += v;
        q += v * v;
    }
    atomicAdd(&s0[col], s);
    atomicAdd(&s1[col], q);
}

__global__ void bn_finalize(const float* __restrict__ s0, const float* __restrict__ s1,
                            const float* __restrict__ g, const float* __restrict__ be,
                            float fn, int c, float* __restrict__ scale, float* __restrict__ shift) {
    int col = threadIdx.x;
    if (col >= c) return;
    float mean = s0[col] / fn;
    float var = s1[col] / fn - mean * mean;
    float sc = g[col] * rsqrtf(var + 1e-5f);
    scale[col] = sc;
    shift[col] = be[col] - mean * sc;
}

__global__ void bn_apply(unsigned short* __restrict__ H, int n8, int c,
                         const float* __restrict__ scale, const float* __restrict__ shift) {
    int cdiv8 = c >> 3;
    for (int i = blockIdx.x * blockDim.x + threadIdx.x; i < n8; i += gridDim.x * blockDim.x) {
        int col = (i % cdiv8) << 3;
        uint4 v = ((const uint4*)H)[i];
        float f[8];
        f[0] = __uint_as_float(v.x << 16); f[1] = __uint_as_float(v.x & 0xffff0000u);
        f[2] = __uint_as_float(v.y << 16); f[3] = __uint_as_float(v.y & 0xffff0000u);
        f[4] = __uint_as_float(v.z << 16); f[5] = __uint_as_float(v.z & 0xffff0000u);
        f[6] = __uint_as_float(v.w << 16); f[7] = __uint_as_float(v.w & 0xffff0000u);
        float4 sc0 = *(const float4*)&scale[col];
        float4 sc1 = *(const float4*)&scale[col + 4];
        float4 sh0 = *(const float4*)&shift[col];
        float4 sh1 = *(const float4*)&shift[col + 4];
        f[0] = fmaxf(f[0] * sc0.x + sh0.x, 0.f);
        f[1] = fmaxf(f[1] * sc0.y + sh0.y, 0.f);
        f[2] = fmaxf(f[2] * sc0.z + sh0.z, 0.f);
        f[3] = fmaxf(f[3] * sc0.w + sh0.w, 0.f);
        f[4] = fmaxf(f[4] * sc1.x + sh1.x, 0.f);
        f[5] = fmaxf(f[5] * sc1.y + sh1.y, 0.f);
        f[6] = fmaxf(f[6] * sc1.z + sh1.z, 0.f);
        f[7] = fmaxf(f[7] * sc1.w + sh1.w, 0.f);
        uint4 o;
        o.x = (unsigned)f2bf(f[0]) | ((unsigned)f2bf(f[1]) << 16);
        o.y = (unsigned)f2bf(f[2]) | ((unsigned)f2bf(f[3]) << 16);
        o.z = (unsigned)f2bf(f[4]) | ((unsigned)f2bf(f[5]) << 16);
        o.w = (unsigned)f2bf(f[6]) | ((unsigned)f2bf(f[7]) << 16);
        ((uint4*)H)[i] = o;
    }
}

// ---------------- host ----------------

extern "C" void kernel_launch(void* const* d_in, const int* in_sizes, int n_in,
                              void* d_out, int out_size, void* d_ws, size_t ws_size,
                              hipStream_t stream) {
    const float* x = (const float*)d_in[0];
    const int* ei = (const int*)d_in[1];
    const float* w1_l = (const float*)d_in[2];
    const float* b1_l = (const float*)d_in[3];
    const float* w1_r = (const float*)d_in[4];
    const float* g1 = (const float*)d_in[5];
    const float* be1 = (const float*)d_in[6];
    const float* w2_l = (const float*)d_in[7];
    const float* b2_l = (const float*)d_in[8];
    const float* w2_r = (const float*)d_in[9];
    const float* g2 = (const float*)d_in[10];
    const float* be2 = (const float*)d_in[11];
    const float* w3_l = (const float*)d_in[12];
    const float* b3_l = (const float*)d_in[13];
    const float* w3_r = (const float*)d_in[14];
    const float* g3 = (const float*)d_in[15];
    const float* be3 = (const float*)d_in[16];
    const float* wc = (const float*)d_in[17];
    const float* bc = (const float*)d_in[18];

    const int N = in_sizes[0] / 128;
    const int E = in_sizes[1] / 2;

    char* ws = (char*)d_ws;
    size_t off = 0;
    auto alloc = [&](size_t bytes) -> char* {
        char* p = ws + off;
        off += (bytes + 255) & ~(size_t)255;
        return p;
    };
    int* cnt = (int*)alloc((size_t)N * 4);
    int* rp = (int*)alloc((size_t)(N + 1) * 4);
    int* pos = (int*)alloc((size_t)N * 4);
    int* csr = (int*)alloc((size_t)E * 4);
    int* flag = (int*)alloc(256);
    unsigned short* xbf = (unsigned short*)alloc((size_t)N * 128 * 2);
    unsigned short* M = (unsigned short*)alloc((size_t)N * 256 * 2);
    unsigned short* Ha = (unsigned short*)alloc((size_t)N * 256 * 2);
    unsigned short* Hb = (unsigned short*)alloc((size_t)N * 256 * 2);
    float* stats = (float*)alloc(4096);  // s0[256] | s1[256] | scale[256] | shift[256]
    float* s0 = stats;
    float* s1 = stats + 256;
    float* scl = stats + 512;
    float* shf = stats + 768;
    (void)ws_size; (void)n_in; (void)out_size;

    // --- CSR build ---
    hipMemsetAsync(cnt, 0, (size_t)N * 4, stream);
    detect_i64<<<1, 1, 0, stream>>>(ei, flag);
    f32_to_bf16_kernel<<<2048, 256, 0, stream>>>(x, xbf, N * 128 / 4);
    hist_kernel<<<2048, 256, 0, stream>>>(ei, flag, E, cnt);
    scan_kernel<<<1, 1024, 0, stream>>>(cnt, rp, pos, N);
    fill_kernel<<<2048, 256, 0, stream>>>(ei, flag, E, pos, csr);

    const int aggGrid = (N + 3) / 4;
    const int rowTiles = (N + 63) / 64;

    // --- layer 1: 128 -> 256 ---
    agg_mean<2><<<aggGrid, 256, 0, stream>>>(xbf, rp, csr, M, N);
    gemm_dual<<<dim3(rowTiles, 4), 256, 0, stream>>>(M, w1_l, xbf, w1_r, b1_l, N, 128, 256, Ha, nullptr);
    hipMemsetAsync(stats, 0, 2048, stream);
    bn_stats<<<1024, 256, 0, stream>>>(Ha, N, 256, s0, s1);
    bn_finalize<<<1, 256, 0, stream>>>(s0, s1, g1, be1, (float)N, 256, scl, shf);
    bn_apply<<<2048, 256, 0, stream>>>(Ha, N * 256 / 8, 256, scl, shf);

    // --- layer 2: 256 -> 256 ---
    agg_mean<4><<<aggGrid, 256, 0, stream>>>(Ha, rp, csr, M, N);
    gemm_dual<<<dim3(rowTiles, 4), 256, 0, stream>>>(M, w2_l, Ha, w2_r, b2_l, N, 256, 256, Hb, nullptr);
    hipMemsetAsync(stats, 0, 2048, stream);
    bn_stats<<<1024, 256, 0, stream>>>(Hb, N, 256, s0, s1);
    bn_finalize<<<1, 256, 0, stream>>>(s0, s1, g2, be2, (float)N, 256, scl, shf);
    bn_apply<<<2048, 256, 0, stream>>>(Hb, N * 256 / 8, 256, scl, shf);

    // --- layer 3: 256 -> 128 ---
    agg_mean<4><<<aggGrid, 256, 0, stream>>>(Hb, rp, csr, M, N);
    gemm_dual<<<dim3(rowTiles, 2), 256, 0, stream>>>(M, w3_l, Hb, w3_r, b3_l, N, 256, 128, Ha, nullptr);
    hipMemsetAsync(stats, 0, 2048, stream);
    bn_stats<<<1024, 256, 0, stream>>>(Ha, N, 128, s0, s1);
    bn_finalize<<<1, 256, 0, stream>>>(s0, s1, g3, be3, (float)N, 128, scl, shf);
    bn_apply<<<2048, 256, 0, stream>>>(Ha, N * 128 / 8, 128, scl, shf);

    // --- classifier: 128 -> 15 (f32 out) ---
    gemm_dual<<<dim3(rowTiles, 1), 256, 0, stream>>>(Ha, wc, nullptr, nullptr, bc, N, 128, 15,
                                                     nullptr, (float*)d_out);
}

// Round 2
// 1518.119 us; speedup vs baseline: 1.4971x; 1.4971x over previous
//
#include <hip/hip_runtime.h>

// GraphSAGE 3-layer + BN(train stats) + ReLU + classifier, MI355X.
// R2: GEMMs moved to bf16 MFMA (16x16x32), fragment-permuted LDS staging,
//     single col-block per GEMM (A read once), weights pre-converted to bf16.

#define DEV static __device__ __forceinline__

typedef __attribute__((ext_vector_type(8))) __bf16 bf16x8;
typedef __attribute__((ext_vector_type(4))) float f32x4;

DEV float bf2f(unsigned short u) { return __uint_as_float(((unsigned)u) << 16); }
DEV unsigned short f2bf(float f) {
    unsigned u = __float_as_uint(f);
    unsigned r = u + 0x7fffu + ((u >> 16) & 1u);  // round-nearest-even
    return (unsigned short)(r >> 16);
}

// ---------------- CSR build ----------------

__global__ void detect_i64(const int* ei, int* flag) {
    int z = (ei[1] == 0) & (ei[3] == 0) & (ei[5] == 0) & (ei[7] == 0);
    *flag = z;
}

__global__ void hist_kernel(const int* __restrict__ ei, const int* __restrict__ flag,
                            int E, int* __restrict__ cnt) {
    const bool i64 = (*flag != 0);
    for (int e = blockIdx.x * blockDim.x + threadIdx.x; e < E; e += gridDim.x * blockDim.x) {
        int d = i64 ? ei[2 * (E + e)] : ei[E + e];
        atomicAdd(&cnt[d], 1);
    }
}

__global__ void scan_kernel(const int* __restrict__ cnt, int* __restrict__ rp,
                            int* __restrict__ pos, int n) {
    __shared__ int sums[1024];
    int t = threadIdx.x;
    int chunk = (n + 1023) >> 10;
    int start = t * chunk;
    int end = min(start + chunk, n);
    int s = 0;
    for (int i = start; i < end; ++i) s += cnt[i];
    sums[t] = s;
    __syncthreads();
    for (int off = 1; off < 1024; off <<= 1) {
        int v = 0;
        if (t >= off) v = sums[t - off];
        __syncthreads();
        sums[t] += v;
        __syncthreads();
    }
    int run = sums[t] - s;
    for (int i = start; i < end; ++i) {
        rp[i] = run;
        pos[i] = run;
        run += cnt[i];
    }
    if (t == 1023) rp[n] = sums[1023];
}

__global__ void fill_kernel(const int* __restrict__ ei, const int* __restrict__ flag,
                            int E, int* __restrict__ pos, int* __restrict__ csr) {
    const bool i64 = (*flag != 0);
    for (int e = blockIdx.x * blockDim.x + threadIdx.x; e < E; e += gridDim.x * blockDim.x) {
        int s = i64 ? ei[2 * e] : ei[e];
        int d = i64 ? ei[2 * (E + e)] : ei[E + e];
        int p = atomicAdd(&pos[d], 1);
        csr[p] = s;
    }
}

// ---------------- dtype convert ----------------

__global__ void f32_to_bf16_kernel(const float* __restrict__ x, unsigned short* __restrict__ o, int n4) {
    for (int i = blockIdx.x * blockDim.x + threadIdx.x; i < n4; i += gridDim.x * blockDim.x) {
        float4 v = ((const float4*)x)[i];
        ushort4 r;
        r.x = f2bf(v.x); r.y = f2bf(v.y); r.z = f2bf(v.z); r.w = f2bf(v.w);
        ((ushort4*)o)[i] = r;
    }
}

struct WConv {
    const float* s[7];
    unsigned short* d[7];
    int n4[7];
};

__global__ void conv_weights(WConv wc) {
    for (int seg = 0; seg < 7; ++seg) {
        const float* s = wc.s[seg];
        unsigned short* d = wc.d[seg];
        int n4 = wc.n4[seg];
        for (int i = blockIdx.x * blockDim.x + threadIdx.x; i < n4; i += gridDim.x * blockDim.x) {
            float4 v = ((const float4*)s)[i];
            ushort4 r;
            r.x = f2bf(v.x); r.y = f2bf(v.y); r.z = f2bf(v.z); r.w = f2bf(v.w);
            ((ushort4*)d)[i] = r;
        }
    }
}

// ---------------- mean aggregation (wave per node) ----------------

template <int VEC>  // cols = 64*VEC
__global__ void agg_mean(const unsigned short* __restrict__ X, const int* __restrict__ rp,
                         const int* __restrict__ csr, unsigned short* __restrict__ M, int n) {
    const int cols = VEC * 64;
    int w = blockIdx.x * (blockDim.x >> 6) + (threadIdx.x >> 6);
    int lane = threadIdx.x & 63;
    if (w >= n) return;
    int beg = rp[w], end = rp[w + 1];
    float acc[VEC];
#pragma unroll
    for (int i = 0; i < VEC; ++i) acc[i] = 0.f;
    for (int e = beg; e < end; ++e) {
        int j = csr[e];
        const unsigned short* p = X + (size_t)j * cols + lane * VEC;
        if (VEC == 2) {
            unsigned u = *(const unsigned*)p;
            acc[0] += __uint_as_float(u << 16);
            acc[1] += __uint_as_float(u & 0xffff0000u);
        } else {
            uint2 u = *(const uint2*)p;
            acc[0] += __uint_as_float(u.x << 16);
            acc[1] += __uint_as_float(u.x & 0xffff0000u);
            acc[2] += __uint_as_float(u.y << 16);
            acc[3] += __uint_as_float(u.y & 0xffff0000u);
        }
    }
    float inv = 1.0f / (float)max(end - beg, 1);
    unsigned short* q = M + (size_t)w * cols + lane * VEC;
    if (VEC == 2) {
        *(ushort2*)q = make_ushort2(f2bf(acc[0] * inv), f2bf(acc[1] * inv));
    } else {
        *(ushort4*)q = make_ushort4(f2bf(acc[0] * inv), f2bf(acc[1] * inv),
                                    f2bf(acc[2] * inv), f2bf(acc[3] * inv));
    }
}

// ---------------- MFMA dual-source GEMM ----------------
// C = A0@W0^T + A1@W1^T + bias.  A: [n,K] bf16 row-major; W: [outc,K] bf16.
// Block: 256 threads (4 waves), tile BM x BN with BN >= outc (single col block).
// LDS layout is fragment-permuted: per 16-wide tile, 64 lanes' 16B fragments
// are consecutive -> staging writes and ds_read_b128 both conflict-free.

template <int BM, int BN, int WM, int WN>
__launch_bounds__(256)
__global__ void gemm_mfma(const unsigned short* __restrict__ A0, const unsigned short* __restrict__ W0,
                          const unsigned short* __restrict__ A1, const unsigned short* __restrict__ W1,
                          const float* __restrict__ bias, int n, int K, int outc,
                          unsigned short* __restrict__ Cbf, float* __restrict__ Cf) {
    constexpr int MT = WM / 16;       // m-tiles per wave
    constexpr int NT = WN / 16;       // n-tiles per wave
    constexpr int WCols = BN / WN;    // wave grid
    __shared__ __align__(16) unsigned short As[BM * 32];  // (BM/16) tiles * 512 shorts
    __shared__ __align__(16) unsigned short Bs[BN * 32];

    const int t = threadIdx.x;
    const int wid = t >> 6, lane = t & 63;
    const int wr = wid / WCols, wc = wid % WCols;
    const int row0 = blockIdx.x * BM;

    f32x4 acc[MT][NT];
#pragma unroll
    for (int i = 0; i < MT; ++i)
#pragma unroll
        for (int j = 0; j < NT; ++j) acc[i][j] = (f32x4){0.f, 0.f, 0.f, 0.f};

    for (int s = 0; s < 2; ++s) {
        const unsigned short* A = s ? A1 : A0;
        const unsigned short* W = s ? W1 : W0;
        if (A == nullptr) break;  // uniform
        for (int kc = 0; kc < K; kc += 32) {
            // stage A: chunk c -> tile mt=c>>6, frag-lane l=c&63 holds
            // A[row0 + mt*16 + (c&15)][kc + ((c>>4)&3)*8 .. +7]
#pragma unroll
            for (int c = t; c < BM * 4; c += 256) {
                int l = c & 63, mt = c >> 6;
                int ar = row0 + mt * 16 + (c & 15);
                int q = (c >> 4) & 3;
                uint4 v = make_uint4(0u, 0u, 0u, 0u);
                if (ar < n) v = *(const uint4*)(A + (size_t)ar * K + kc + q * 8);
                *(uint4*)&As[mt * 512 + l * 8] = v;
            }
#pragma unroll
            for (int c = t; c < BN * 4; c += 256) {
                int l = c & 63, nt = c >> 6;
                int col = nt * 16 + (c & 15);
                int q = (c >> 4) & 3;
                uint4 v = make_uint4(0u, 0u, 0u, 0u);
                if (col < outc) v = *(const uint4*)(W + (size_t)col * K + kc + q * 8);
                *(uint4*)&Bs[nt * 512 + l * 8] = v;
            }
            __syncthreads();
            bf16x8 af[MT], bf[NT];
#pragma unroll
            for (int mt = 0; mt < MT; ++mt)
                af[mt] = *(const bf16x8*)&As[(wr * MT + mt) * 512 + lane * 8];
#pragma unroll
            for (int nt = 0; nt < NT; ++nt)
                bf[nt] = *(const bf16x8*)&Bs[(wc * NT + nt) * 512 + lane * 8];
#pragma unroll
            for (int mt = 0; mt < MT; ++mt)
#pragma unroll
                for (int nt = 0; nt < NT; ++nt)
                    acc[mt][nt] = __builtin_amdgcn_mfma_f32_16x16x32_bf16(af[mt], bf[nt], acc[mt][nt], 0, 0, 0);
            __syncthreads();
        }
    }

    // epilogue: C/D map col=lane&15, row=(lane>>4)*4+reg  [m89-verified]
#pragma unroll
    for (int mt = 0; mt < MT; ++mt) {
#pragma unroll
        for (int nt = 0; nt < NT; ++nt) {
            int col = wc * WN + nt * 16 + (lane & 15);
            int rbase = row0 + wr * WM + mt * 16 + ((lane >> 4) << 2);
            bool cok = col < outc;
            float bv = cok ? bias[col] : 0.f;
#pragma unroll
            for (int i = 0; i < 4; ++i) {
                int r = rbase + i;
                if (r < n && cok) {
                    float v = acc[mt][nt][i] + bv;
                    if (Cf) Cf[(size_t)r * outc + col] = v;
                    else Cbf[(size_t)r * outc + col] = f2bf(v);
                }
            }
        }
    }
}

// ---------------- BatchNorm (training stats) + ReLU ----------------

__global__ void bn_stats(const unsigned short* __restrict__ H, int n, int c,
                         float* __restrict__ s0, float* __restrict__ s1) {
    int col = threadIdx.x;
    if (col >= c) return;
    float s = 0.f, q = 0.f;
    for (int r = blockIdx.x; r < n; r += gridDim.x) {
        float v = bf2f(H[(size_t)r * c + col]);
        s += v;
        q += v * v;
    }
    atomicAdd(&s0[col], s);
    atomicAdd(&s1[col], q);
}

__global__ void bn_finalize(const float* __restrict__ s0, const float* __restrict__ s1,
                            const float* __restrict__ g, const float* __restrict__ be,
                            float fn, int c, float* __restrict__ scale, float* __restrict__ shift) {
    int col = threadIdx.x;
    if (col >= c) return;
    float mean = s0[col] / fn;
    float var = s1[col] / fn - mean * mean;
    float sc = g[col] * rsqrtf(var + 1e-5f);
    scale[col] = sc;
    shift[col] = be[col] - mean * sc;
}

__global__ void bn_apply(unsigned short* __restrict__ H, int n8, int c,
                         const float* __restrict__ scale, const float* __restrict__ shift) {
    int cdiv8 = c >> 3;
    for (int i = blockIdx.x * blockDim.x + threadIdx.x; i < n8; i += gridDim.x * blockDim.x) {
        int col = (i % cdiv8) << 3;
        uint4 v = ((const uint4*)H)[i];
        float f[8];
        f[0] = __uint_as_float(v.x << 16); f[1] = __uint_as_float(v.x & 0xffff0000u);
        f[2] = __uint_as_float(v.y << 16); f[3] = __uint_as_float(v.y & 0xffff0000u);
        f[4] = __uint_as_float(v.z << 16); f[5] = __uint_as_float(v.z & 0xffff0000u);
        f[6] = __uint_as_float(v.w << 16); f[7] = __uint_as_float(v.w & 0xffff0000u);
        float4 sc0 = *(const float4*)&scale[col];
        float4 sc1 = *(const float4*)&scale[col + 4];
        float4 sh0 = *(const float4*)&shift[col];
        float4 sh1 = *(const float4*)&shift[col + 4];
        f[0] = fmaxf(f[0] * sc0.x + sh0.x, 0.f);
        f[1] = fmaxf(f[1] * sc0.y + sh0.y, 0.f);
        f[2] = fmaxf(f[2] * sc0.z + sh0.z, 0.f);
        f[3] = fmaxf(f[3] * sc0.w + sh0.w, 0.f);
        f[4] = fmaxf(f[4] * sc1.x + sh1.x, 0.f);
        f[5] = fmaxf(f[5] * sc1.y + sh1.y, 0.f);
        f[6] = fmaxf(f[6] * sc1.z + sh1.z, 0.f);
        f[7] = fmaxf(f[7] * sc1.w + sh1.w, 0.f);
        uint4 o;
        o.x = (unsigned)f2bf(f[0]) | ((unsigned)f2bf(f[1]) << 16);
        o.y = (unsigned)f2bf(f[2]) | ((unsigned)f2bf(f[3]) << 16);
        o.z = (unsigned)f2bf(f[4]) | ((unsigned)f2bf(f[5]) << 16);
        o.w = (unsigned)f2bf(f[6]) | ((unsigned)f2bf(f[7]) << 16);
        ((uint4*)H)[i] = o;
    }
}

// ---------------- host ----------------

extern "C" void kernel_launch(void* const* d_in, const int* in_sizes, int n_in,
                              void* d_out, int out_size, void* d_ws, size_t ws_size,
                              hipStream_t stream) {
    const float* x = (const float*)d_in[0];
    const int* ei = (const int*)d_in[1];
    const float* w1_l = (const float*)d_in[2];
    const float* b1_l = (const float*)d_in[3];
    const float* w1_r = (const float*)d_in[4];
    const float* g1 = (const float*)d_in[5];
    const float* be1 = (const float*)d_in[6];
    const float* w2_l = (const float*)d_in[7];
    const float* b2_l = (const float*)d_in[8];
    const float* w2_r = (const float*)d_in[9];
    const float* g2 = (const float*)d_in[10];
    const float* be2 = (const float*)d_in[11];
    const float* w3_l = (const float*)d_in[12];
    const float* b3_l = (const float*)d_in[13];
    const float* w3_r = (const float*)d_in[14];
    const float* g3 = (const float*)d_in[15];
    const float* be3 = (const float*)d_in[16];
    const float* wcf = (const float*)d_in[17];
    const float* bc = (const float*)d_in[18];

    const int N = in_sizes[0] / 128;
    const int E = in_sizes[1] / 2;

    char* ws = (char*)d_ws;
    size_t off = 0;
    auto alloc = [&](size_t bytes) -> char* {
        char* p = ws + off;
        off += (bytes + 255) & ~(size_t)255;
        return p;
    };
    int* cnt = (int*)alloc((size_t)N * 4);
    int* rp = (int*)alloc((size_t)(N + 1) * 4);
    int* pos = (int*)alloc((size_t)N * 4);
    int* csr = (int*)alloc((size_t)E * 4);
    int* flag = (int*)alloc(256);
    unsigned short* xbf = (unsigned short*)alloc((size_t)N * 128 * 2);
    unsigned short* M = (unsigned short*)alloc((size_t)N * 256 * 2);
    unsigned short* Ha = (unsigned short*)alloc((size_t)N * 256 * 2);
    unsigned short* Hb = (unsigned short*)alloc((size_t)N * 256 * 2);
    float* stats = (float*)alloc(4096);
    float* s0 = stats;
    float* s1 = stats + 256;
    float* scl = stats + 512;
    float* shf = stats + 768;
    // bf16 weights
    unsigned short* w1l_b = (unsigned short*)alloc(256 * 128 * 2);
    unsigned short* w1r_b = (unsigned short*)alloc(256 * 128 * 2);
    unsigned short* w2l_b = (unsigned short*)alloc(256 * 256 * 2);
    unsigned short* w2r_b = (unsigned short*)alloc(256 * 256 * 2);
    unsigned short* w3l_b = (unsigned short*)alloc(128 * 256 * 2);
    unsigned short* w3r_b = (unsigned short*)alloc(128 * 256 * 2);
    unsigned short* wc_b = (unsigned short*)alloc(15 * 128 * 2);
    (void)ws_size; (void)n_in; (void)out_size;

    // --- CSR build + conversions ---
    hipMemsetAsync(cnt, 0, (size_t)N * 4, stream);
    detect_i64<<<1, 1, 0, stream>>>(ei, flag);
    f32_to_bf16_kernel<<<2048, 256, 0, stream>>>(x, xbf, N * 128 / 4);
    WConv wconv;
    wconv.s[0] = w1_l; wconv.d[0] = w1l_b; wconv.n4[0] = 256 * 128 / 4;
    wconv.s[1] = w1_r; wconv.d[1] = w1r_b; wconv.n4[1] = 256 * 128 / 4;
    wconv.s[2] = w2_l; wconv.d[2] = w2l_b; wconv.n4[2] = 256 * 256 / 4;
    wconv.s[3] = w2_r; wconv.d[3] = w2r_b; wconv.n4[3] = 256 * 256 / 4;
    wconv.s[4] = w3_l; wconv.d[4] = w3l_b; wconv.n4[4] = 128 * 256 / 4;
    wconv.s[5] = w3_r; wconv.d[5] = w3r_b; wconv.n4[5] = 128 * 256 / 4;
    wconv.s[6] = wcf;  wconv.d[6] = wc_b;  wconv.n4[6] = 15 * 128 / 4;
    conv_weights<<<256, 256, 0, stream>>>(wconv);
    hist_kernel<<<2048, 256, 0, stream>>>(ei, flag, E, cnt);
    scan_kernel<<<1, 1024, 0, stream>>>(cnt, rp, pos, N);
    fill_kernel<<<2048, 256, 0, stream>>>(ei, flag, E, pos, csr);

    const int aggGrid = (N + 3) / 4;
    const int rowTiles = (N + 63) / 64;

    // --- layer 1: 128 -> 256 ---
    agg_mean<2><<<aggGrid, 256, 0, stream>>>(xbf, rp, csr, M, N);
    gemm_mfma<64, 256, 64, 64><<<rowTiles, 256, 0, stream>>>(M, w1l_b, xbf, w1r_b, b1_l, N, 128, 256, Ha, nullptr);
    hipMemsetAsync(stats, 0, 2048, stream);
    bn_stats<<<1024, 256, 0, stream>>>(Ha, N, 256, s0, s1);
    bn_finalize<<<1, 256, 0, stream>>>(s0, s1, g1, be1, (float)N, 256, scl, shf);
    bn_apply<<<2048, 256, 0, stream>>>(Ha, N * 256 / 8, 256, scl, shf);

    // --- layer 2: 256 -> 256 ---
    agg_mean<4><<<aggGrid, 256, 0, stream>>>(Ha, rp, csr, M, N);
    gemm_mfma<64, 256, 64, 64><<<rowTiles, 256, 0, stream>>>(M, w2l_b, Ha, w2r_b, b2_l, N, 256, 256, Hb, nullptr);
    hipMemsetAsync(stats, 0, 2048, stream);
    bn_stats<<<1024, 256, 0, stream>>>(Hb, N, 256, s0, s1);
    bn_finalize<<<1, 256, 0, stream>>>(s0, s1, g2, be2, (float)N, 256, scl, shf);
    bn_apply<<<2048, 256, 0, stream>>>(Hb, N * 256 / 8, 256, scl, shf);

    // --- layer 3: 256 -> 128 ---
    agg_mean<4><<<aggGrid, 256, 0, stream>>>(Hb, rp, csr, M, N);
    gemm_mfma<64, 128, 64, 32><<<rowTiles, 256, 0, stream>>>(M, w3l_b, Hb, w3r_b, b3_l, N, 256, 128, Ha, nullptr);
    hipMemsetAsync(stats, 0, 2048, stream);
    bn_stats<<<1024, 256, 0, stream>>>(Ha, N, 128, s0, s1);
    bn_finalize<<<1, 256, 0, stream>>>(s0, s1, g3, be3, (float)N, 128, scl, shf);
    bn_apply<<<2048, 256, 0, stream>>>(Ha, N * 128 / 8, 128, scl, shf);

    // --- classifier: 128 -> 15 (f32 out) ---
    gemm_mfma<64, 16, 16, 16><<<rowTiles, 256, 0, stream>>>(Ha, wc_b, nullptr, nullptr, bc, N, 128, 15,
                                                            nullptr, (float*)d_out);
}

// Round 3
// 1133.218 us; speedup vs baseline: 2.0056x; 1.3397x over previous
//
#include <hip/hip_runtime.h>

// GraphSAGE 3-layer + BN(train stats) + ReLU + classifier, MI355X.
// R3: parallel scan (was 228us single-block), layer-3 commuted (GEMM first,
//     aggregate 128 cols not 256), bn_apply fused into consumers (gather +
//     GEMM A-staging), 2x-unrolled gather loop.

#define DEV static __device__ __forceinline__

typedef __attribute__((ext_vector_type(8))) __bf16 bf16x8;
typedef __attribute__((ext_vector_type(4))) float f32x4;

DEV float bf2f(unsigned short u) { return __uint_as_float(((unsigned)u) << 16); }
DEV unsigned short f2bf(float f) {
    unsigned u = __float_as_uint(f);
    unsigned r = u + 0x7fffu + ((u >> 16) & 1u);  // round-nearest-even
    return (unsigned short)(r >> 16);
}
// bn+relu on a packed pair of bf16 (low = earlier element)
DEV unsigned bnpack2(unsigned u, float s0, float s1, float h0, float h1) {
    float lo = fmaxf(__uint_as_float(u << 16) * s0 + h0, 0.f);
    float hi = fmaxf(__uint_as_float(u & 0xffff0000u) * s1 + h1, 0.f);
    return (unsigned)f2bf(lo) | ((unsigned)f2bf(hi) << 16);
}

// ---------------- CSR build ----------------

__global__ void detect_i64(const int* ei, int* flag) {
    int z = (ei[1] == 0) & (ei[3] == 0) & (ei[5] == 0) & (ei[7] == 0);
    *flag = z;
}

__global__ void hist_kernel(const int* __restrict__ ei, const int* __restrict__ flag,
                            int E, int* __restrict__ cnt) {
    const bool i64 = (*flag != 0);
    for (int e = blockIdx.x * blockDim.x + threadIdx.x; e < E; e += gridDim.x * blockDim.x) {
        int d = i64 ? ei[2 * (E + e)] : ei[E + e];
        atomicAdd(&cnt[d], 1);
    }
}

// block b sums cnt[b*2048 .. +2048) -> part[b]
__global__ void scan_part(const int* __restrict__ cnt, int* __restrict__ part, int n) {
    __shared__ int red[256];
    int b = blockIdx.x, t = threadIdx.x;
    int base = b * 2048 + t * 8;
    int s = 0;
#pragma unroll
    for (int i = 0; i < 8; ++i)
        if (base + i < n) s += cnt[base + i];
    red[t] = s;
    __syncthreads();
    for (int off = 128; off > 0; off >>= 1) {
        if (t < off) red[t] += red[t + off];
        __syncthreads();
    }
    if (t == 0) part[b] = red[0];
}

// single-thread exclusive scan of part[nb] (nb <= ~64), also writes rp[n]=total
__global__ void scan_mid(int* part, int* rp, int n, int nb) {
    if (threadIdx.x == 0 && blockIdx.x == 0) {
        int run = 0;
        for (int b = 0; b < nb; ++b) {
            int v = part[b];
            part[b] = run;
            run += v;
        }
        rp[n] = run;
    }
}

__global__ void scan_final(const int* __restrict__ cnt, const int* __restrict__ part,
                           int* __restrict__ rp, int* __restrict__ pos, int n) {
    __shared__ int red[256];
    int b = blockIdx.x, t = threadIdx.x;
    int base = b * 2048 + t * 8;
    int v[8];
    int s = 0;
#pragma unroll
    for (int i = 0; i < 8; ++i) {
        v[i] = (base + i < n) ? cnt[base + i] : 0;
        s += v[i];
    }
    red[t] = s;
    __syncthreads();
    for (int off = 1; off < 256; off <<= 1) {
        int u = (t >= off) ? red[t - off] : 0;
        __syncthreads();
        red[t] += u;
        __syncthreads();
    }
    int pre = part[b] + red[t] - s;  // exclusive prefix for this thread's 8
#pragma unroll
    for (int i = 0; i < 8; ++i) {
        if (base + i < n) {
            rp[base + i] = pre;
            pos[base + i] = pre;
        }
        pre += v[i];
    }
}

__global__ void fill_kernel(const int* __restrict__ ei, const int* __restrict__ flag,
                            int E, int* __restrict__ pos, int* __restrict__ csr) {
    const bool i64 = (*flag != 0);
    for (int e = blockIdx.x * blockDim.x + threadIdx.x; e < E; e += gridDim.x * blockDim.x) {
        int s = i64 ? ei[2 * e] : ei[e];
        int d = i64 ? ei[2 * (E + e)] : ei[E + e];
        int p = atomicAdd(&pos[d], 1);
        csr[p] = s;
    }
}

// ---------------- dtype convert ----------------

__global__ void f32_to_bf16_kernel(const float* __restrict__ x, unsigned short* __restrict__ o, int n4) {
    for (int i = blockIdx.x * blockDim.x + threadIdx.x; i < n4; i += gridDim.x * blockDim.x) {
        float4 v = ((const float4*)x)[i];
        ushort4 r;
        r.x = f2bf(v.x); r.y = f2bf(v.y); r.z = f2bf(v.z); r.w = f2bf(v.w);
        ((ushort4*)o)[i] = r;
    }
}

struct WConv {
    const float* s[7];
    unsigned short* d[7];
    int n4[7];
};

__global__ void conv_weights(WConv wc) {
    for (int seg = 0; seg < 7; ++seg) {
        const float* s = wc.s[seg];
        unsigned short* d = wc.d[seg];
        int n4 = wc.n4[seg];
        for (int i = blockIdx.x * blockDim.x + threadIdx.x; i < n4; i += gridDim.x * blockDim.x) {
            float4 v = ((const float4*)s)[i];
            ushort4 r;
            r.x = f2bf(v.x); r.y = f2bf(v.y); r.z = f2bf(v.z); r.w = f2bf(v.w);
            ((ushort4*)d)[i] = r;
        }
    }
}

// ---------------- mean aggregation (wave per node), optional fused BN+ReLU on source ----

template <int VEC>  // cols = 64*VEC
__global__ void agg_mean_bn(const unsigned short* __restrict__ X, const int* __restrict__ rp,
                            const int* __restrict__ csr, const float* __restrict__ scl,
                            const float* __restrict__ shf, unsigned short* __restrict__ M, int n) {
    const int cols = VEC * 64;
    int w = blockIdx.x * (blockDim.x >> 6) + (threadIdx.x >> 6);
    int lane = threadIdx.x & 63;
    if (w >= n) return;
    const bool bn = (scl != nullptr);
    float sc[VEC], sh[VEC];
#pragma unroll
    for (int i = 0; i < VEC; ++i) { sc[i] = 1.f; sh[i] = 0.f; }
    if (bn) {
#pragma unroll
        for (int i = 0; i < VEC; ++i) {
            sc[i] = scl[lane * VEC + i];
            sh[i] = shf[lane * VEC + i];
        }
    }
    int beg = rp[w], end = rp[w + 1];
    float acc[VEC];
#pragma unroll
    for (int i = 0; i < VEC; ++i) acc[i] = 0.f;

    int e = beg;
    for (; e + 2 <= end; e += 2) {
        int j0 = csr[e], j1 = csr[e + 1];
        if (VEC == 2) {
            unsigned u0 = *(const unsigned*)(X + (size_t)j0 * cols + lane * 2);
            unsigned u1 = *(const unsigned*)(X + (size_t)j1 * cols + lane * 2);
            float f0 = __uint_as_float(u0 << 16), f1 = __uint_as_float(u0 & 0xffff0000u);
            float g0 = __uint_as_float(u1 << 16), g1 = __uint_as_float(u1 & 0xffff0000u);
            if (bn) {
                f0 = fmaxf(f0 * sc[0] + sh[0], 0.f); f1 = fmaxf(f1 * sc[1] + sh[1], 0.f);
                g0 = fmaxf(g0 * sc[0] + sh[0], 0.f); g1 = fmaxf(g1 * sc[1] + sh[1], 0.f);
            }
            acc[0] += f0 + g0; acc[1] += f1 + g1;
        } else {
            uint2 u0 = *(const uint2*)(X + (size_t)j0 * cols + lane * 4);
            uint2 u1 = *(const uint2*)(X + (size_t)j1 * cols + lane * 4);
            float f[4], g[4];
            f[0] = __uint_as_float(u0.x << 16); f[1] = __uint_as_float(u0.x & 0xffff0000u);
            f[2] = __uint_as_float(u0.y << 16); f[3] = __uint_as_float(u0.y & 0xffff0000u);
            g[0] = __uint_as_float(u1.x << 16); g[1] = __uint_as_float(u1.x & 0xffff0000u);
            g[2] = __uint_as_float(u1.y << 16); g[3] = __uint_as_float(u1.y & 0xffff0000u);
            if (bn) {
#pragma unroll
                for (int i = 0; i < 4; ++i) {
                    f[i] = fmaxf(f[i] * sc[i] + sh[i], 0.f);
                    g[i] = fmaxf(g[i] * sc[i] + sh[i], 0.f);
                }
            }
#pragma unroll
            for (int i = 0; i < 4; ++i) acc[i] += f[i] + g[i];
        }
    }
    if (e < end) {
        int j0 = csr[e];
        if (VEC == 2) {
            unsigned u0 = *(const unsigned*)(X + (size_t)j0 * cols + lane * 2);
            float f0 = __uint_as_float(u0 << 16), f1 = __uint_as_float(u0 & 0xffff0000u);
            if (bn) { f0 = fmaxf(f0 * sc[0] + sh[0], 0.f); f1 = fmaxf(f1 * sc[1] + sh[1], 0.f); }
            acc[0] += f0; acc[1] += f1;
        } else {
            uint2 u0 = *(const uint2*)(X + (size_t)j0 * cols + lane * 4);
            float f[4];
            f[0] = __uint_as_float(u0.x << 16); f[1] = __uint_as_float(u0.x & 0xffff0000u);
            f[2] = __uint_as_float(u0.y << 16); f[3] = __uint_as_float(u0.y & 0xffff0000u);
#pragma unroll
            for (int i = 0; i < 4; ++i) {
                if (bn) f[i] = fmaxf(f[i] * sc[i] + sh[i], 0.f);
                acc[i] += f[i];
            }
        }
    }
    float inv = 1.0f / (float)max(end - beg, 1);
    unsigned short* q = M + (size_t)w * cols + lane * VEC;
    if (VEC == 2) {
        *(ushort2*)q = make_ushort2(f2bf(acc[0] * inv), f2bf(acc[1] * inv));
    } else {
        *(ushort4*)q = make_ushort4(f2bf(acc[0] * inv), f2bf(acc[1] * inv),
                                    f2bf(acc[2] * inv), f2bf(acc[3] * inv));
    }
}

// layer-3 post-GEMM aggregation: H[i][c] = mean_j Yc[j][c] + Yc[i][128+c] + bias[c]
// Yc rows are 256 bf16: cols 0..127 = Y (aggregate), 128..255 = Z (self term).
__global__ void agg_post(const unsigned short* __restrict__ Yc, const int* __restrict__ rp,
                         const int* __restrict__ csr, const float* __restrict__ bias,
                         unsigned short* __restrict__ H, int n) {
    int w = blockIdx.x * (blockDim.x >> 6) + (threadIdx.x >> 6);
    int lane = threadIdx.x & 63;
    if (w >= n) return;
    int beg = rp[w], end = rp[w + 1];
    float a0 = 0.f, a1 = 0.f;
    int e = beg;
    for (; e + 2 <= end; e += 2) {
        int j0 = csr[e], j1 = csr[e + 1];
        unsigned u0 = *(const unsigned*)(Yc + (size_t)j0 * 256 + lane * 2);
        unsigned u1 = *(const unsigned*)(Yc + (size_t)j1 * 256 + lane * 2);
        a0 += __uint_as_float(u0 << 16) + __uint_as_float(u1 << 16);
        a1 += __uint_as_float(u0 & 0xffff0000u) + __uint_as_float(u1 & 0xffff0000u);
    }
    if (e < end) {
        unsigned u0 = *(const unsigned*)(Yc + (size_t)csr[e] * 256 + lane * 2);
        a0 += __uint_as_float(u0 << 16);
        a1 += __uint_as_float(u0 & 0xffff0000u);
    }
    float inv = 1.0f / (float)max(end - beg, 1);
    unsigned uz = *(const unsigned*)(Yc + (size_t)w * 256 + 128 + lane * 2);
    float2 bv = *(const float2*)(bias + lane * 2);
    float r0 = a0 * inv + __uint_as_float(uz << 16) + bv.x;
    float r1 = a1 * inv + __uint_as_float(uz & 0xffff0000u) + bv.y;
    *(ushort2*)(H + (size_t)w * 128 + lane * 2) = make_ushort2(f2bf(r0), f2bf(r1));
}

// ---------------- MFMA dual-source GEMM with optional fused BN+ReLU on A ----
// C = f(A0)@W0^T + f(A1)@W1^T + bias, f = relu(bn) if bn ptrs given.

template <int BM, int BN, int WM, int WN>
__launch_bounds__(256)
__global__ void gemm_mfma(const unsigned short* __restrict__ A0, const unsigned short* __restrict__ W0,
                          const float* __restrict__ bnS0, const float* __restrict__ bnH0,
                          const unsigned short* __restrict__ A1, const unsigned short* __restrict__ W1,
                          const float* __restrict__ bnS1, const float* __restrict__ bnH1,
                          const float* __restrict__ bias, int n, int K, int outc,
                          unsigned short* __restrict__ Cbf, float* __restrict__ Cf) {
    constexpr int MT = WM / 16;
    constexpr int NT = WN / 16;
    constexpr int WCols = BN / WN;
    __shared__ __align__(16) unsigned short As[BM * 32];
    __shared__ __align__(16) unsigned short Bs[BN * 32];

    const int t = threadIdx.x;
    const int wid = t >> 6, lane = t & 63;
    const int wr = wid / WCols, wcc = wid % WCols;
    const int row0 = blockIdx.x * BM;

    f32x4 acc[MT][NT];
#pragma unroll
    for (int i = 0; i < MT; ++i)
#pragma unroll
        for (int j = 0; j < NT; ++j) acc[i][j] = (f32x4){0.f, 0.f, 0.f, 0.f};

    const unsigned short* Aarr[2] = {A0, A1};
    const unsigned short* Warr[2] = {W0, W1};
    const float* Sarr[2] = {bnS0, bnS1};
    const float* Harr[2] = {bnH0, bnH1};

    for (int s = 0; s < 2; ++s) {
        const unsigned short* A = Aarr[s];
        const unsigned short* W = Warr[s];
        const float* bs = Sarr[s];
        const float* bh = Harr[s];
        if (A == nullptr) break;  // uniform
        for (int kc = 0; kc < K; kc += 32) {
#pragma unroll
            for (int c = t; c < BM * 4; c += 256) {
                int l = c & 63, mt = c >> 6;
                int ar = row0 + mt * 16 + (c & 15);
                int q = (c >> 4) & 3;
                uint4 v = make_uint4(0u, 0u, 0u, 0u);
                if (ar < n) {
                    v = *(const uint4*)(A + (size_t)ar * K + kc + q * 8);
                    if (bs) {
                        const float4* sp = (const float4*)(bs + kc + q * 8);
                        const float4* hp = (const float4*)(bh + kc + q * 8);
                        float4 s0 = sp[0], s1 = sp[1], h0 = hp[0], h1 = hp[1];
                        v.x = bnpack2(v.x, s0.x, s0.y, h0.x, h0.y);
                        v.y = bnpack2(v.y, s0.z, s0.w, h0.z, h0.w);
                        v.z = bnpack2(v.z, s1.x, s1.y, h1.x, h1.y);
                        v.w = bnpack2(v.w, s1.z, s1.w, h1.z, h1.w);
                    }
                }
                *(uint4*)&As[mt * 512 + l * 8] = v;
            }
#pragma unroll
            for (int c = t; c < BN * 4; c += 256) {
                int l = c & 63, nt = c >> 6;
                int col = nt * 16 + (c & 15);
                int q = (c >> 4) & 3;
                uint4 v = make_uint4(0u, 0u, 0u, 0u);
                if (col < outc) v = *(const uint4*)(W + (size_t)col * K + kc + q * 8);
                *(uint4*)&Bs[nt * 512 + l * 8] = v;
            }
            __syncthreads();
            bf16x8 af[MT], bfr[NT];
#pragma unroll
            for (int mt = 0; mt < MT; ++mt)
                af[mt] = *(const bf16x8*)&As[(wr * MT + mt) * 512 + lane * 8];
#pragma unroll
            for (int nt = 0; nt < NT; ++nt)
                bfr[nt] = *(const bf16x8*)&Bs[(wcc * NT + nt) * 512 + lane * 8];
#pragma unroll
            for (int mt = 0; mt < MT; ++mt)
#pragma unroll
                for (int nt = 0; nt < NT; ++nt)
                    acc[mt][nt] = __builtin_amdgcn_mfma_f32_16x16x32_bf16(af[mt], bfr[nt], acc[mt][nt], 0, 0, 0);
            __syncthreads();
        }
    }

    // epilogue: C/D map col=lane&15, row=(lane>>4)*4+reg
#pragma unroll
    for (int mt = 0; mt < MT; ++mt) {
#pragma unroll
        for (int nt = 0; nt < NT; ++nt) {
            int col = wcc * WN + nt * 16 + (lane & 15);
            int rbase = row0 + wr * WM + mt * 16 + ((lane >> 4) << 2);
            bool cok = col < outc;
            float bv = (bias != nullptr && cok) ? bias[col] : 0.f;
#pragma unroll
            for (int i = 0; i < 4; ++i) {
                int r = rbase + i;
                if (r < n && cok) {
                    float v = acc[mt][nt][i] + bv;
                    if (Cf) Cf[(size_t)r * outc + col] = v;
                    else Cbf[(size_t)r * outc + col] = f2bf(v);
                }
            }
        }
    }
}

// ---------------- BatchNorm stats ----------------

__global__ void bn_stats(const unsigned short* __restrict__ H, int n, int c,
                         float* __restrict__ s0, float* __restrict__ s1) {
    int col = threadIdx.x;
    if (col >= c) return;
    float s = 0.f, q = 0.f;
    for (int r = blockIdx.x; r < n; r += gridDim.x) {
        float v = bf2f(H[(size_t)r * c + col]);
        s += v;
        q += v * v;
    }
    atomicAdd(&s0[col], s);
    atomicAdd(&s1[col], q);
}

__global__ void bn_finalize(const float* __restrict__ s0, const float* __restrict__ s1,
                            const float* __restrict__ g, const float* __restrict__ be,
                            float fn, int c, float* __restrict__ scale, float* __restrict__ shift) {
    int col = threadIdx.x;
    if (col >= c) return;
    float mean = s0[col] / fn;
    float var = s1[col] / fn - mean * mean;
    float sc = g[col] * rsqrtf(var + 1e-5f);
    scale[col] = sc;
    shift[col] = be[col] - mean * sc;
}

// ---------------- host ----------------

extern "C" void kernel_launch(void* const* d_in, const int* in_sizes, int n_in,
                              void* d_out, int out_size, void* d_ws, size_t ws_size,
                              hipStream_t stream) {
    const float* x = (const float*)d_in[0];
    const int* ei = (const int*)d_in[1];
    const float* w1_l = (const float*)d_in[2];
    const float* b1_l = (const float*)d_in[3];
    const float* w1_r = (const float*)d_in[4];
    const float* g1 = (const float*)d_in[5];
    const float* be1 = (const float*)d_in[6];
    const float* w2_l = (const float*)d_in[7];
    const float* b2_l = (const float*)d_in[8];
    const float* w2_r = (const float*)d_in[9];
    const float* g2 = (const float*)d_in[10];
    const float* be2 = (const float*)d_in[11];
    const float* w3_l = (const float*)d_in[12];
    const float* b3_l = (const float*)d_in[13];
    const float* w3_r = (const float*)d_in[14];
    const float* g3 = (const float*)d_in[15];
    const float* be3 = (const float*)d_in[16];
    const float* wcf = (const float*)d_in[17];
    const float* bc = (const float*)d_in[18];

    const int N = in_sizes[0] / 128;
    const int E = in_sizes[1] / 2;
    const int nb = (N + 2047) / 2048;

    char* ws = (char*)d_ws;
    size_t off = 0;
    auto alloc = [&](size_t bytes) -> char* {
        char* p = ws + off;
        off += (bytes + 255) & ~(size_t)255;
        return p;
    };
    int* cnt = (int*)alloc((size_t)N * 4);
    int* rp = (int*)alloc((size_t)(N + 1) * 4);
    int* pos = (int*)alloc((size_t)N * 4);
    int* csr = (int*)alloc((size_t)E * 4);
    int* flag = (int*)alloc(256);
    int* part = (int*)alloc((size_t)nb * 4);
    unsigned short* xbf = (unsigned short*)alloc((size_t)N * 128 * 2);
    unsigned short* M = (unsigned short*)alloc((size_t)N * 256 * 2);   // also Yc in L3
    unsigned short* Ha = (unsigned short*)alloc((size_t)N * 256 * 2);  // h1 raw; later h3 raw
    unsigned short* Hb = (unsigned short*)alloc((size_t)N * 256 * 2);  // h2 raw
    float* stats = (float*)alloc(64 * 4 * 4 + 6 * 256 * 4);
    float* s0 = stats;
    float* s1 = stats + 256;
    float* scl1 = stats + 512, *shf1 = stats + 768;
    float* scl2 = stats + 1024, *shf2 = stats + 1280;
    float* scl3 = stats + 1536, *shf3 = stats + 1792;
    unsigned short* w1l_b = (unsigned short*)alloc(256 * 128 * 2);
    unsigned short* w1r_b = (unsigned short*)alloc(256 * 128 * 2);
    unsigned short* w2l_b = (unsigned short*)alloc(256 * 256 * 2);
    unsigned short* w2r_b = (unsigned short*)alloc(256 * 256 * 2);
    unsigned short* w3cat = (unsigned short*)alloc(256 * 256 * 2);  // rows 0-127 w3_l, 128-255 w3_r
    unsigned short* wc_b = (unsigned short*)alloc(15 * 128 * 2);
    (void)ws_size; (void)n_in; (void)out_size;

    // --- CSR build + conversions ---
    hipMemsetAsync(cnt, 0, (size_t)N * 4, stream);
    detect_i64<<<1, 1, 0, stream>>>(ei, flag);
    f32_to_bf16_kernel<<<2048, 256, 0, stream>>>(x, xbf, N * 128 / 4);
    WConv wconv;
    wconv.s[0] = w1_l; wconv.d[0] = w1l_b; wconv.n4[0] = 256 * 128 / 4;
    wconv.s[1] = w1_r; wconv.d[1] = w1r_b; wconv.n4[1] = 256 * 128 / 4;
    wconv.s[2] = w2_l; wconv.d[2] = w2l_b; wconv.n4[2] = 256 * 256 / 4;
    wconv.s[3] = w2_r; wconv.d[3] = w2r_b; wconv.n4[3] = 256 * 256 / 4;
    wconv.s[4] = w3_l; wconv.d[4] = w3cat; wconv.n4[4] = 128 * 256 / 4;
    wconv.s[5] = w3_r; wconv.d[5] = w3cat + 128 * 256; wconv.n4[5] = 128 * 256 / 4;
    wconv.s[6] = wcf;  wconv.d[6] = wc_b;  wconv.n4[6] = 15 * 128 / 4;
    conv_weights<<<256, 256, 0, stream>>>(wconv);
    hist_kernel<<<2048, 256, 0, stream>>>(ei, flag, E, cnt);
    scan_part<<<nb, 256, 0, stream>>>(cnt, part, N);
    scan_mid<<<1, 64, 0, stream>>>(part, rp, N, nb);
    scan_final<<<nb, 256, 0, stream>>>(cnt, part, rp, pos, N);
    fill_kernel<<<2048, 256, 0, stream>>>(ei, flag, E, pos, csr);

    const int aggGrid = (N + 3) / 4;
    const int rowTiles = (N + 63) / 64;

    // --- layer 1: 128 -> 256 (aggregate-first; x has no BN) ---
    agg_mean_bn<2><<<aggGrid, 256, 0, stream>>>(xbf, rp, csr, nullptr, nullptr, M, N);
    gemm_mfma<64, 256, 64, 64><<<rowTiles, 256, 0, stream>>>(
        M, w1l_b, nullptr, nullptr, xbf, w1r_b, nullptr, nullptr, b1_l, N, 128, 256, Ha, nullptr);
    hipMemsetAsync(stats, 0, 2048, stream);
    bn_stats<<<1024, 256, 0, stream>>>(Ha, N, 256, s0, s1);
    bn_finalize<<<1, 256, 0, stream>>>(s0, s1, g1, be1, (float)N, 256, scl1, shf1);

    // --- layer 2: 256 -> 256 (bn1 fused into gather + GEMM A1 staging) ---
    agg_mean_bn<4><<<aggGrid, 256, 0, stream>>>(Ha, rp, csr, scl1, shf1, M, N);
    gemm_mfma<64, 256, 64, 64><<<rowTiles, 256, 0, stream>>>(
        M, w2l_b, nullptr, nullptr, Ha, w2r_b, scl1, shf1, b2_l, N, 256, 256, Hb, nullptr);
    hipMemsetAsync(stats, 0, 2048, stream);
    bn_stats<<<1024, 256, 0, stream>>>(Hb, N, 256, s0, s1);
    bn_finalize<<<1, 256, 0, stream>>>(s0, s1, g2, be2, (float)N, 256, scl2, shf2);

    // --- layer 3: 256 -> 128, GEMM-first: [Y|Z] = relu(bn2(h2)) @ [w3l|w3r]^T ---
    gemm_mfma<64, 256, 64, 64><<<rowTiles, 256, 0, stream>>>(
        Hb, w3cat, scl2, shf2, nullptr, nullptr, nullptr, nullptr, nullptr, N, 256, 256, M, nullptr);
    agg_post<<<aggGrid, 256, 0, stream>>>(M, rp, csr, b3_l, Ha, N);
    hipMemsetAsync(stats, 0, 2048, stream);
    bn_stats<<<1024, 256, 0, stream>>>(Ha, N, 128, s0, s1);
    bn_finalize<<<1, 256, 0, stream>>>(s0, s1, g3, be3, (float)N, 128, scl3, shf3);

    // --- classifier: relu(bn3(h3)) @ wc^T + bc -> f32 d_out ---
    gemm_mfma<64, 16, 16, 16><<<rowTiles, 256, 0, stream>>>(
        Ha, wc_b, scl3, shf3, nullptr, nullptr, nullptr, nullptr, bc, N, 128, 15,
        nullptr, (float*)d_out);
}

// Round 4
// 1052.155 us; speedup vs baseline: 2.1601x; 1.0770x over previous
//
#include <hip/hip_runtime.h>

// GraphSAGE 3-layer + BN(train stats) + ReLU + classifier, MI355X.
// R4: CSR build rewritten as bucketed two-level radix (bucket_hist ->
//     bucket_offsets -> scatter8 -> fine_csr). Every global write region is
//     single-block-owned => no cross-XCD cacheline sharing (R3: fill_kernel
//     wrote 106MB HBM for a 6.4MB array). GEMM/agg/BN unchanged.

#define DEV static __device__ __forceinline__

typedef __attribute__((ext_vector_type(8))) __bf16 bf16x8;
typedef __attribute__((ext_vector_type(4))) float f32x4;

DEV float bf2f(unsigned short u) { return __uint_as_float(((unsigned)u) << 16); }
DEV unsigned short f2bf(float f) {
    unsigned u = __float_as_uint(f);
    unsigned r = u + 0x7fffu + ((u >> 16) & 1u);  // round-nearest-even
    return (unsigned short)(r >> 16);
}
// bn+relu on a packed pair of bf16 (low = earlier element)
DEV unsigned bnpack2(unsigned u, float s0, float s1, float h0, float h1) {
    float lo = fmaxf(__uint_as_float(u << 16) * s0 + h0, 0.f);
    float hi = fmaxf(__uint_as_float(u & 0xffff0000u) * s1 + h1, 0.f);
    return (unsigned)f2bf(lo) | ((unsigned)f2bf(hi) << 16);
}

// ---------------- CSR build (bucketed two-level) ----------------
// bucket = dst >> 9 (512 nodes/bucket). NB <= 256 assumed (N <= 131072).

__global__ void detect_i64(const int* ei, int* flag) {
    int z = (ei[1] == 0) & (ei[3] == 0) & (ei[5] == 0) & (ei[7] == 0);
    *flag = z;
}

// G blocks; block g histograms its edge chunk into hist2[g][NB]
__global__ void bucket_hist(const int* __restrict__ ei, const int* __restrict__ flag,
                            int E, int* __restrict__ hist2, int NB, int chunk) {
    __shared__ int h[256];
    const int g = blockIdx.x, t = threadIdx.x;
    const bool i64 = (*flag != 0);
    h[t] = 0;
    __syncthreads();
    int beg = g * chunk, end = min(beg + chunk, E);
    for (int e = beg + t; e < end; e += 256) {
        int d = i64 ? ei[2 * (E + e)] : ei[E + e];
        atomicAdd(&h[d >> 9], 1);
    }
    __syncthreads();
    if (t < NB) hist2[g * NB + t] = h[t];
}

// single block: bucket totals -> exclusive scan -> bucketBase;
// hist2[g][b] converted in place to global scatter offsets; rp[N] = E.
__global__ void bucket_offsets(int* __restrict__ hist2, int* __restrict__ bucketBase,
                               int* __restrict__ rp, int N, int G, int NB) {
    __shared__ int tot[256];
    const int t = threadIdx.x;
    int sum = 0;
    if (t < NB)
        for (int g = 0; g < G; ++g) sum += hist2[g * NB + t];
    tot[t] = sum;
    __syncthreads();
    for (int off = 1; off < 256; off <<= 1) {
        int v = (t >= off) ? tot[t - off] : 0;
        __syncthreads();
        tot[t] += v;
        __syncthreads();
    }
    int base = tot[t] - sum;  // exclusive
    if (t < NB) {
        bucketBase[t] = base;
        int run = base;
        for (int g = 0; g < G; ++g) {
            int v = hist2[g * NB + t];
            hist2[g * NB + t] = run;
            run += v;
        }
        if (t == NB - 1) {
            bucketBase[NB] = tot[t];
            rp[N] = tot[t];
        }
    }
}

// block g re-reads its chunk, scatters 8B (src,dst) records into per-(g,b)
// sequential sub-streams (offsets pre-computed in hist2).
__global__ void scatter8(const int* __restrict__ ei, const int* __restrict__ flag,
                         int E, const int* __restrict__ hist2, uint2* __restrict__ ebuf,
                         int NB, int chunk) {
    __shared__ int off[256];
    const int g = blockIdx.x, t = threadIdx.x;
    const bool i64 = (*flag != 0);
    if (t < NB) off[t] = hist2[g * NB + t];
    __syncthreads();
    int beg = g * chunk, end = min(beg + chunk, E);
    for (int e = beg + t; e < end; e += 256) {
        int s = i64 ? ei[2 * e] : ei[e];
        int d = i64 ? ei[2 * (E + e)] : ei[E + e];
        int p = atomicAdd(&off[d >> 9], 1);
        ebuf[p] = make_uint2((unsigned)s, (unsigned)d);
    }
}

// block per bucket: LDS count over 512 nodes -> LDS scan -> rp, then place
// src into the bucket's contiguous csr slice (single-block-owned region).
__global__ void fine_csr(const uint2* __restrict__ ebuf, const int* __restrict__ bucketBase,
                         int N, int* __restrict__ rp, int* __restrict__ csr) {
    __shared__ int cnt[512];
    __shared__ int red[256];
    const int b = blockIdx.x, t = threadIdx.x;
    const int node0 = b << 9;
    cnt[t] = 0;
    cnt[t + 256] = 0;
    __syncthreads();
    const int ebeg = bucketBase[b], eend = bucketBase[b + 1];
    for (int e = ebeg + t; e < eend; e += 256) {
        uint2 r = ebuf[e];
        atomicAdd(&cnt[r.y & 511], 1);
    }
    __syncthreads();
    int c0 = cnt[2 * t], c1 = cnt[2 * t + 1];
    int s = c0 + c1;
    red[t] = s;
    __syncthreads();
    for (int off = 1; off < 256; off <<= 1) {
        int v = (t >= off) ? red[t - off] : 0;
        __syncthreads();
        red[t] += v;
        __syncthreads();
    }
    int pre = red[t] - s;  // exclusive prefix of this thread's pair
    int n0 = node0 + 2 * t;
    if (n0 < N) rp[n0] = ebeg + pre;
    if (n0 + 1 < N) rp[n0 + 1] = ebeg + pre + c0;
    __syncthreads();
    cnt[2 * t] = ebeg + pre;            // reuse as running positions
    cnt[2 * t + 1] = ebeg + pre + c0;
    __syncthreads();
    for (int e = ebeg + t; e < eend; e += 256) {
        uint2 r = ebuf[e];
        int p = atomicAdd(&cnt[r.y & 511], 1);
        csr[p] = (int)r.x;
    }
}

// ---------------- dtype convert ----------------

__global__ void f32_to_bf16_kernel(const float* __restrict__ x, unsigned short* __restrict__ o, int n4) {
    for (int i = blockIdx.x * blockDim.x + threadIdx.x; i < n4; i += gridDim.x * blockDim.x) {
        float4 v = ((const float4*)x)[i];
        ushort4 r;
        r.x = f2bf(v.x); r.y = f2bf(v.y); r.z = f2bf(v.z); r.w = f2bf(v.w);
        ((ushort4*)o)[i] = r;
    }
}

struct WConv {
    const float* s[7];
    unsigned short* d[7];
    int n4[7];
};

__global__ void conv_weights(WConv wc) {
    for (int seg = 0; seg < 7; ++seg) {
        const float* s = wc.s[seg];
        unsigned short* d = wc.d[seg];
        int n4 = wc.n4[seg];
        for (int i = blockIdx.x * blockDim.x + threadIdx.x; i < n4; i += gridDim.x * blockDim.x) {
            float4 v = ((const float4*)s)[i];
            ushort4 r;
            r.x = f2bf(v.x); r.y = f2bf(v.y); r.z = f2bf(v.z); r.w = f2bf(v.w);
            ((ushort4*)d)[i] = r;
        }
    }
}

// ---------------- mean aggregation (wave per node), optional fused BN+ReLU on source ----

template <int VEC>  // cols = 64*VEC
__global__ void agg_mean_bn(const unsigned short* __restrict__ X, const int* __restrict__ rp,
                            const int* __restrict__ csr, const float* __restrict__ scl,
                            const float* __restrict__ shf, unsigned short* __restrict__ M, int n) {
    const int cols = VEC * 64;
    int w = blockIdx.x * (blockDim.x >> 6) + (threadIdx.x >> 6);
    int lane = threadIdx.x & 63;
    if (w >= n) return;
    const bool bn = (scl != nullptr);
    float sc[VEC], sh[VEC];
#pragma unroll
    for (int i = 0; i < VEC; ++i) { sc[i] = 1.f; sh[i] = 0.f; }
    if (bn) {
#pragma unroll
        for (int i = 0; i < VEC; ++i) {
            sc[i] = scl[lane * VEC + i];
            sh[i] = shf[lane * VEC + i];
        }
    }
    int beg = rp[w], end = rp[w + 1];
    float acc[VEC];
#pragma unroll
    for (int i = 0; i < VEC; ++i) acc[i] = 0.f;

    int e = beg;
    for (; e + 2 <= end; e += 2) {
        int j0 = csr[e], j1 = csr[e + 1];
        if (VEC == 2) {
            unsigned u0 = *(const unsigned*)(X + (size_t)j0 * cols + lane * 2);
            unsigned u1 = *(const unsigned*)(X + (size_t)j1 * cols + lane * 2);
            float f0 = __uint_as_float(u0 << 16), f1 = __uint_as_float(u0 & 0xffff0000u);
            float g0 = __uint_as_float(u1 << 16), g1 = __uint_as_float(u1 & 0xffff0000u);
            if (bn) {
                f0 = fmaxf(f0 * sc[0] + sh[0], 0.f); f1 = fmaxf(f1 * sc[1] + sh[1], 0.f);
                g0 = fmaxf(g0 * sc[0] + sh[0], 0.f); g1 = fmaxf(g1 * sc[1] + sh[1], 0.f);
            }
            acc[0] += f0 + g0; acc[1] += f1 + g1;
        } else {
            uint2 u0 = *(const uint2*)(X + (size_t)j0 * cols + lane * 4);
            uint2 u1 = *(const uint2*)(X + (size_t)j1 * cols + lane * 4);
            float f[4], g[4];
            f[0] = __uint_as_float(u0.x << 16); f[1] = __uint_as_float(u0.x & 0xffff0000u);
            f[2] = __uint_as_float(u0.y << 16); f[3] = __uint_as_float(u0.y & 0xffff0000u);
            g[0] = __uint_as_float(u1.x << 16); g[1] = __uint_as_float(u1.x & 0xffff0000u);
            g[2] = __uint_as_float(u1.y << 16); g[3] = __uint_as_float(u1.y & 0xffff0000u);
            if (bn) {
#pragma unroll
                for (int i = 0; i < 4; ++i) {
                    f[i] = fmaxf(f[i] * sc[i] + sh[i], 0.f);
                    g[i] = fmaxf(g[i] * sc[i] + sh[i], 0.f);
                }
            }
#pragma unroll
            for (int i = 0; i < 4; ++i) acc[i] += f[i] + g[i];
        }
    }
    if (e < end) {
        int j0 = csr[e];
        if (VEC == 2) {
            unsigned u0 = *(const unsigned*)(X + (size_t)j0 * cols + lane * 2);
            float f0 = __uint_as_float(u0 << 16), f1 = __uint_as_float(u0 & 0xffff0000u);
            if (bn) { f0 = fmaxf(f0 * sc[0] + sh[0], 0.f); f1 = fmaxf(f1 * sc[1] + sh[1], 0.f); }
            acc[0] += f0; acc[1] += f1;
        } else {
            uint2 u0 = *(const uint2*)(X + (size_t)j0 * cols + lane * 4);
            float f[4];
            f[0] = __uint_as_float(u0.x << 16); f[1] = __uint_as_float(u0.x & 0xffff0000u);
            f[2] = __uint_as_float(u0.y << 16); f[3] = __uint_as_float(u0.y & 0xffff0000u);
#pragma unroll
            for (int i = 0; i < 4; ++i) {
                if (bn) f[i] = fmaxf(f[i] * sc[i] + sh[i], 0.f);
                acc[i] += f[i];
            }
        }
    }
    float inv = 1.0f / (float)max(end - beg, 1);
    unsigned short* q = M + (size_t)w * cols + lane * VEC;
    if (VEC == 2) {
        *(ushort2*)q = make_ushort2(f2bf(acc[0] * inv), f2bf(acc[1] * inv));
    } else {
        *(ushort4*)q = make_ushort4(f2bf(acc[0] * inv), f2bf(acc[1] * inv),
                                    f2bf(acc[2] * inv), f2bf(acc[3] * inv));
    }
}

// layer-3 post-GEMM aggregation: H[i][c] = mean_j Yc[j][c] + Yc[i][128+c] + bias[c]
__global__ void agg_post(const unsigned short* __restrict__ Yc, const int* __restrict__ rp,
                         const int* __restrict__ csr, const float* __restrict__ bias,
                         unsigned short* __restrict__ H, int n) {
    int w = blockIdx.x * (blockDim.x >> 6) + (threadIdx.x >> 6);
    int lane = threadIdx.x & 63;
    if (w >= n) return;
    int beg = rp[w], end = rp[w + 1];
    float a0 = 0.f, a1 = 0.f;
    int e = beg;
    for (; e + 2 <= end; e += 2) {
        int j0 = csr[e], j1 = csr[e + 1];
        unsigned u0 = *(const unsigned*)(Yc + (size_t)j0 * 256 + lane * 2);
        unsigned u1 = *(const unsigned*)(Yc + (size_t)j1 * 256 + lane * 2);
        a0 += __uint_as_float(u0 << 16) + __uint_as_float(u1 << 16);
        a1 += __uint_as_float(u0 & 0xffff0000u) + __uint_as_float(u1 & 0xffff0000u);
    }
    if (e < end) {
        unsigned u0 = *(const unsigned*)(Yc + (size_t)csr[e] * 256 + lane * 2);
        a0 += __uint_as_float(u0 << 16);
        a1 += __uint_as_float(u0 & 0xffff0000u);
    }
    float inv = 1.0f / (float)max(end - beg, 1);
    unsigned uz = *(const unsigned*)(Yc + (size_t)w * 256 + 128 + lane * 2);
    float2 bv = *(const float2*)(bias + lane * 2);
    float r0 = a0 * inv + __uint_as_float(uz << 16) + bv.x;
    float r1 = a1 * inv + __uint_as_float(uz & 0xffff0000u) + bv.y;
    *(ushort2*)(H + (size_t)w * 128 + lane * 2) = make_ushort2(f2bf(r0), f2bf(r1));
}

// ---------------- MFMA dual-source GEMM with optional fused BN+ReLU on A ----

template <int BM, int BN, int WM, int WN>
__launch_bounds__(256)
__global__ void gemm_mfma(const unsigned short* __restrict__ A0, const unsigned short* __restrict__ W0,
                          const float* __restrict__ bnS0, const float* __restrict__ bnH0,
                          const unsigned short* __restrict__ A1, const unsigned short* __restrict__ W1,
                          const float* __restrict__ bnS1, const float* __restrict__ bnH1,
                          const float* __restrict__ bias, int n, int K, int outc,
                          unsigned short* __restrict__ Cbf, float* __restrict__ Cf) {
    constexpr int MT = WM / 16;
    constexpr int NT = WN / 16;
    constexpr int WCols = BN / WN;
    __shared__ __align__(16) unsigned short As[BM * 32];
    __shared__ __align__(16) unsigned short Bs[BN * 32];

    const int t = threadIdx.x;
    const int wid = t >> 6, lane = t & 63;
    const int wr = wid / WCols, wcc = wid % WCols;
    const int row0 = blockIdx.x * BM;

    f32x4 acc[MT][NT];
#pragma unroll
    for (int i = 0; i < MT; ++i)
#pragma unroll
        for (int j = 0; j < NT; ++j) acc[i][j] = (f32x4){0.f, 0.f, 0.f, 0.f};

    const unsigned short* Aarr[2] = {A0, A1};
    const unsigned short* Warr[2] = {W0, W1};
    const float* Sarr[2] = {bnS0, bnS1};
    const float* Harr[2] = {bnH0, bnH1};

    for (int s = 0; s < 2; ++s) {
        const unsigned short* A = Aarr[s];
        const unsigned short* W = Warr[s];
        const float* bs = Sarr[s];
        const float* bh = Harr[s];
        if (A == nullptr) break;  // uniform
        for (int kc = 0; kc < K; kc += 32) {
#pragma unroll
            for (int c = t; c < BM * 4; c += 256) {
                int l = c & 63, mt = c >> 6;
                int ar = row0 + mt * 16 + (c & 15);
                int q = (c >> 4) & 3;
                uint4 v = make_uint4(0u, 0u, 0u, 0u);
                if (ar < n) {
                    v = *(const uint4*)(A + (size_t)ar * K + kc + q * 8);
                    if (bs) {
                        const float4* sp = (const float4*)(bs + kc + q * 8);
                        const float4* hp = (const float4*)(bh + kc + q * 8);
                        float4 s0 = sp[0], s1 = sp[1], h0 = hp[0], h1 = hp[1];
                        v.x = bnpack2(v.x, s0.x, s0.y, h0.x, h0.y);
                        v.y = bnpack2(v.y, s0.z, s0.w, h0.z, h0.w);
                        v.z = bnpack2(v.z, s1.x, s1.y, h1.x, h1.y);
                        v.w = bnpack2(v.w, s1.z, s1.w, h1.z, h1.w);
                    }
                }
                *(uint4*)&As[mt * 512 + l * 8] = v;
            }
#pragma unroll
            for (int c = t; c < BN * 4; c += 256) {
                int l = c & 63, nt = c >> 6;
                int col = nt * 16 + (c & 15);
                int q = (c >> 4) & 3;
                uint4 v = make_uint4(0u, 0u, 0u, 0u);
                if (col < outc) v = *(const uint4*)(W + (size_t)col * K + kc + q * 8);
                *(uint4*)&Bs[nt * 512 + l * 8] = v;
            }
            __syncthreads();
            bf16x8 af[MT], bfr[NT];
#pragma unroll
            for (int mt = 0; mt < MT; ++mt)
                af[mt] = *(const bf16x8*)&As[(wr * MT + mt) * 512 + lane * 8];
#pragma unroll
            for (int nt = 0; nt < NT; ++nt)
                bfr[nt] = *(const bf16x8*)&Bs[(wcc * NT + nt) * 512 + lane * 8];
#pragma unroll
            for (int mt = 0; mt < MT; ++mt)
#pragma unroll
                for (int nt = 0; nt < NT; ++nt)
                    acc[mt][nt] = __builtin_amdgcn_mfma_f32_16x16x32_bf16(af[mt], bfr[nt], acc[mt][nt], 0, 0, 0);
            __syncthreads();
        }
    }

    // epilogue: C/D map col=lane&15, row=(lane>>4)*4+reg
#pragma unroll
    for (int mt = 0; mt < MT; ++mt) {
#pragma unroll
        for (int nt = 0; nt < NT; ++nt) {
            int col = wcc * WN + nt * 16 + (lane & 15);
            int rbase = row0 + wr * WM + mt * 16 + ((lane >> 4) << 2);
            bool cok = col < outc;
            float bv = (bias != nullptr && cok) ? bias[col] : 0.f;
#pragma unroll
            for (int i = 0; i < 4; ++i) {
                int r = rbase + i;
                if (r < n && cok) {
                    float v = acc[mt][nt][i] + bv;
                    if (Cf) Cf[(size_t)r * outc + col] = v;
                    else Cbf[(size_t)r * outc + col] = f2bf(v);
                }
            }
        }
    }
}

// ---------------- BatchNorm stats ----------------

__global__ void bn_stats(const unsigned short* __restrict__ H, int n, int c,
                         float* __restrict__ s0, float* __restrict__ s1) {
    int col = threadIdx.x;
    if (col >= c) return;
    float s = 0.f, q = 0.f;
    for (int r = blockIdx.x; r < n; r += gridDim.x) {
        float v = bf2f(H[(size_t)r * c + col]);
        s += v;
        q += v * v;
    }
    atomicAdd(&s0[col], s);
    atomicAdd(&s1[col], q);
}

__global__ void bn_finalize(const float* __restrict__ s0, const float* __restrict__ s1,
                            const float* __restrict__ g, const float* __restrict__ be,
                            float fn, int c, float* __restrict__ scale, float* __restrict__ shift) {
    int col = threadIdx.x;
    if (col >= c) return;
    float mean = s0[col] / fn;
    float var = s1[col] / fn - mean * mean;
    float sc = g[col] * rsqrtf(var + 1e-5f);
    scale[col] = sc;
    shift[col] = be[col] - mean * sc;
}

// ---------------- host ----------------

extern "C" void kernel_launch(void* const* d_in, const int* in_sizes, int n_in,
                              void* d_out, int out_size, void* d_ws, size_t ws_size,
                              hipStream_t stream) {
    const float* x = (const float*)d_in[0];
    const int* ei = (const int*)d_in[1];
    const float* w1_l = (const float*)d_in[2];
    const float* b1_l = (const float*)d_in[3];
    const float* w1_r = (const float*)d_in[4];
    const float* g1 = (const float*)d_in[5];
    const float* be1 = (const float*)d_in[6];
    const float* w2_l = (const float*)d_in[7];
    const float* b2_l = (const float*)d_in[8];
    const float* w2_r = (const float*)d_in[9];
    const float* g2 = (const float*)d_in[10];
    const float* be2 = (const float*)d_in[11];
    const float* w3_l = (const float*)d_in[12];
    const float* b3_l = (const float*)d_in[13];
    const float* w3_r = (const float*)d_in[14];
    const float* g3 = (const float*)d_in[15];
    const float* be3 = (const float*)d_in[16];
    const float* wcf = (const float*)d_in[17];
    const float* bc = (const float*)d_in[18];

    const int N = in_sizes[0] / 128;
    const int E = in_sizes[1] / 2;
    const int NB = (N + 511) >> 9;          // buckets of 512 nodes (NB <= 256)
    const int G = 256;                      // radix pass grid
    const int chunk = (E + G - 1) / G;

    char* ws = (char*)d_ws;
    size_t off = 0;
    auto alloc = [&](size_t bytes) -> char* {
        char* p = ws + off;
        off += (bytes + 255) & ~(size_t)255;
        return p;
    };
    int* rp = (int*)alloc((size_t)(N + 1) * 4);
    int* csr = (int*)alloc((size_t)E * 4);
    int* flag = (int*)alloc(256);
    int* hist2 = (int*)alloc((size_t)G * NB * 4);
    int* bucketBase = (int*)alloc((size_t)(NB + 1) * 4);
    uint2* ebuf = (uint2*)alloc((size_t)E * 8);
    unsigned short* xbf = (unsigned short*)alloc((size_t)N * 128 * 2);
    unsigned short* M = (unsigned short*)alloc((size_t)N * 256 * 2);   // also Yc in L3
    unsigned short* Ha = (unsigned short*)alloc((size_t)N * 256 * 2);  // h1 raw; later h3 raw
    unsigned short* Hb = (unsigned short*)alloc((size_t)N * 256 * 2);  // h2 raw
    float* stats = (float*)alloc(8 * 256 * 4);
    float* s0 = stats;
    float* s1 = stats + 256;
    float* scl1 = stats + 512, *shf1 = stats + 768;
    float* scl2 = stats + 1024, *shf2 = stats + 1280;
    float* scl3 = stats + 1536, *shf3 = stats + 1792;
    unsigned short* w1l_b = (unsigned short*)alloc(256 * 128 * 2);
    unsigned short* w1r_b = (unsigned short*)alloc(256 * 128 * 2);
    unsigned short* w2l_b = (unsigned short*)alloc(256 * 256 * 2);
    unsigned short* w2r_b = (unsigned short*)alloc(256 * 256 * 2);
    unsigned short* w3cat = (unsigned short*)alloc(256 * 256 * 2);  // rows 0-127 w3_l, 128-255 w3_r
    unsigned short* wc_b = (unsigned short*)alloc(15 * 128 * 2);
    (void)ws_size; (void)n_in; (void)out_size;

    // --- CSR build (bucketed) + conversions ---
    detect_i64<<<1, 1, 0, stream>>>(ei, flag);
    f32_to_bf16_kernel<<<2048, 256, 0, stream>>>(x, xbf, N * 128 / 4);
    WConv wconv;
    wconv.s[0] = w1_l; wconv.d[0] = w1l_b; wconv.n4[0] = 256 * 128 / 4;
    wconv.s[1] = w1_r; wconv.d[1] = w1r_b; wconv.n4[1] = 256 * 128 / 4;
    wconv.s[2] = w2_l; wconv.d[2] = w2l_b; wconv.n4[2] = 256 * 256 / 4;
    wconv.s[3] = w2_r; wconv.d[3] = w2r_b; wconv.n4[3] = 256 * 256 / 4;
    wconv.s[4] = w3_l; wconv.d[4] = w3cat; wconv.n4[4] = 128 * 256 / 4;
    wconv.s[5] = w3_r; wconv.d[5] = w3cat + 128 * 256; wconv.n4[5] = 128 * 256 / 4;
    wconv.s[6] = wcf;  wconv.d[6] = wc_b;  wconv.n4[6] = 15 * 128 / 4;
    conv_weights<<<256, 256, 0, stream>>>(wconv);
    bucket_hist<<<G, 256, 0, stream>>>(ei, flag, E, hist2, NB, chunk);
    bucket_offsets<<<1, 256, 0, stream>>>(hist2, bucketBase, rp, N, G, NB);
    scatter8<<<G, 256, 0, stream>>>(ei, flag, E, hist2, ebuf, NB, chunk);
    fine_csr<<<NB, 256, 0, stream>>>(ebuf, bucketBase, N, rp, csr);

    const int aggGrid = (N + 3) / 4;
    const int rowTiles = (N + 63) / 64;

    // --- layer 1: 128 -> 256 (aggregate-first; x has no BN) ---
    agg_mean_bn<2><<<aggGrid, 256, 0, stream>>>(xbf, rp, csr, nullptr, nullptr, M, N);
    gemm_mfma<64, 256, 64, 64><<<rowTiles, 256, 0, stream>>>(
        M, w1l_b, nullptr, nullptr, xbf, w1r_b, nullptr, nullptr, b1_l, N, 128, 256, Ha, nullptr);
    hipMemsetAsync(stats, 0, 2048, stream);
    bn_stats<<<1024, 256, 0, stream>>>(Ha, N, 256, s0, s1);
    bn_finalize<<<1, 256, 0, stream>>>(s0, s1, g1, be1, (float)N, 256, scl1, shf1);

    // --- layer 2: 256 -> 256 (bn1 fused into gather + GEMM A1 staging) ---
    agg_mean_bn<4><<<aggGrid, 256, 0, stream>>>(Ha, rp, csr, scl1, shf1, M, N);
    gemm_mfma<64, 256, 64, 64><<<rowTiles, 256, 0, stream>>>(
        M, w2l_b, nullptr, nullptr, Ha, w2r_b, scl1, shf1, b2_l, N, 256, 256, Hb, nullptr);
    hipMemsetAsync(stats, 0, 2048, stream);
    bn_stats<<<1024, 256, 0, stream>>>(Hb, N, 256, s0, s1);
    bn_finalize<<<1, 256, 0, stream>>>(s0, s1, g2, be2, (float)N, 256, scl2, shf2);

    // --- layer 3: 256 -> 128, GEMM-first: [Y|Z] = relu(bn2(h2)) @ [w3l|w3r]^T ---
    gemm_mfma<64, 256, 64, 64><<<rowTiles, 256, 0, stream>>>(
        Hb, w3cat, scl2, shf2, nullptr, nullptr, nullptr, nullptr, nullptr, N, 256, 256, M, nullptr);
    agg_post<<<aggGrid, 256, 0, stream>>>(M, rp, csr, b3_l, Ha, N);
    hipMemsetAsync(stats, 0, 2048, stream);
    bn_stats<<<1024, 256, 0, stream>>>(Ha, N, 128, s0, s1);
    bn_finalize<<<1, 256, 0, stream>>>(s0, s1, g3, be3, (float)N, 128, scl3, shf3);

    // --- classifier: relu(bn3(h3)) @ wc^T + bc -> f32 d_out ---
    gemm_mfma<64, 16, 16, 16><<<rowTiles, 256, 0, stream>>>(
        Ha, wc_b, scl3, shf3, nullptr, nullptr, nullptr, nullptr, bc, N, 128, 15,
        nullptr, (float*)d_out);
}